// Round 1
// baseline (304.435 us; speedup 1.0000x reference)
//
#include <hip/hip_runtime.h>
#include <math.h>

// MoE router: X[8192,4096] fp32 @ Wt[4096,64] -> logits[8192,64] -> top2 -> softmax -> scatter.
// d_out = probs[8192*64] ++ routing_map[8192*64] (floats).
//
// ws layout: Wt (4096*64 floats = 1MB) | partial logits [8][8192][64] floats (16MB)

#define HDIM 4096
#define NEXP 64
#define NTOK 8192
#define HG 8            // h-groups across blocks
#define SLICES 4        // h-slices (waves) per block
#define HS (HDIM / (HG * SLICES))  // 128 h-values per thread
#define TPB 64          // tokens per block (one per lane)

// ---------------- kernel 0: transpose W[64][4096] -> Wt[4096][64] ----------------
__global__ void wtrans_kernel(const float* __restrict__ W, float* __restrict__ Wt) {
    __shared__ float tile[64][65];           // [h][e], pad 65 -> 2-way max
    int h0 = blockIdx.x * 64;
    int lx = threadIdx.x & 63;
    int ly = threadIdx.x >> 6;               // 0..3
    #pragma unroll
    for (int p = 0; p < 16; ++p) {
        int e = p * 4 + ly;
        tile[lx][e] = W[(size_t)e * HDIM + h0 + lx];   // coalesced over lx
    }
    __syncthreads();
    #pragma unroll
    for (int p = 0; p < 16; ++p) {
        int hh = p * 4 + ly;
        Wt[(size_t)(h0 + hh) * NEXP + lx] = tile[hh][lx];  // coalesced over lx
    }
}

// ---------------- kernel 1: partial logits ----------------
__global__ __launch_bounds__(256, 4) void logits_kernel(
        const float* __restrict__ X, const float* __restrict__ Wt,
        float* __restrict__ part) {
    const int tg   = blockIdx.x >> 3;        // token group 0..127
    const int hg   = blockIdx.x & 7;         // h group 0..7
    const int lane = threadIdx.x & 63;       // token within group
    // slice is wave-uniform by construction; readfirstlane makes it provably so,
    // which keeps h (and hence all Wt addresses) scalar -> s_load broadcast.
    const int slice = __builtin_amdgcn_readfirstlane((int)(threadIdx.x >> 6));
    const int token = tg * TPB + lane;
    const int h0    = (hg * SLICES + slice) * HS;

    const float* xrow = X + (size_t)token * HDIM + h0;
    const float* wrow = Wt + (size_t)h0 * NEXP;

    float acc[NEXP];
    #pragma unroll
    for (int e = 0; e < NEXP; ++e) acc[e] = 0.f;

    for (int i = 0; i < HS; i += 4) {
        float4 x4 = *reinterpret_cast<const float4*>(xrow + i);   // 16B/lane, lanes = tokens
        float xv[4] = {x4.x, x4.y, x4.z, x4.w};
        #pragma unroll
        for (int j = 0; j < 4; ++j) {
            const float* w = wrow + (size_t)(i + j) * NEXP;       // wave-uniform address
            #pragma unroll
            for (int e = 0; e < NEXP; ++e)
                acc[e] = fmaf(xv[j], w[e], acc[e]);               // SGPR-broadcast W
        }
    }

    // reduce the 4 slice-partials; expert-chunked (2 x 32) to keep LDS at ~33KB
    __shared__ float buf[SLICES][TPB][33];   // pad 33 -> 2-way max
    for (int c = 0; c < 2; ++c) {
        __syncthreads();                     // protect buf reuse
        float* myrow = &buf[slice][lane][0];
        #pragma unroll
        for (int i = 0; i < 32; ++i) myrow[i] = acc[c * 32 + i];
        __syncthreads();
        int ec = threadIdx.x & 31;
        int t0 = threadIdx.x >> 5;           // 0..7
        #pragma unroll
        for (int p = 0; p < 8; ++p) {
            int t = p * 8 + t0;
            float s = buf[0][t][ec] + buf[1][t][ec] + buf[2][t][ec] + buf[3][t][ec];
            part[((size_t)hg * NTOK + (size_t)tg * TPB + t) * NEXP + c * 32 + ec] = s;
        }
    }
}

// ---------------- kernel 2: reduce HG partials, top-2 softmax, scatter ----------------
__global__ __launch_bounds__(256) void topk_kernel(
        const float* __restrict__ part, float* __restrict__ probs,
        float* __restrict__ rmap) {
    const int wave = threadIdx.x >> 6;
    const int lane = threadIdx.x & 63;       // lane = expert
    const int token = blockIdx.x * 4 + wave;

    const float* p = part + (size_t)token * NEXP + lane;
    float v = 0.f;
    #pragma unroll
    for (int hg = 0; hg < HG; ++hg) v += p[(size_t)hg * NTOK * NEXP];

    // top-1 (lower index wins ties, like lax.top_k)
    float m1 = v; int i1 = lane;
    #pragma unroll
    for (int s = 32; s > 0; s >>= 1) {
        float om = __shfl_xor(m1, s, 64);
        int   oi = __shfl_xor(i1, s, 64);
        if (om > m1 || (om == m1 && oi < i1)) { m1 = om; i1 = oi; }
    }
    // top-2: exclude i1
    float vx = (lane == i1) ? -INFINITY : v;
    float m2 = vx; int i2 = lane;
    #pragma unroll
    for (int s = 32; s > 0; s >>= 1) {
        float om = __shfl_xor(m2, s, 64);
        int   oi = __shfl_xor(i2, s, 64);
        if (om > m2 || (om == m2 && oi < i2)) { m2 = om; i2 = oi; }
    }

    // softmax over (m1, m2); m2 - m1 <= 0 so expf is safe
    float e2 = expf(m2 - m1);
    float p1 = 1.f / (1.f + e2);
    float p2 = 1.f - p1;

    float prob = (lane == i1) ? p1 : ((lane == i2) ? p2 : 0.f);
    float flag = (lane == i1 || lane == i2) ? 1.f : 0.f;
    probs[(size_t)token * NEXP + lane] = prob;   // coalesced 64 dwords
    rmap [(size_t)token * NEXP + lane] = flag;
}

extern "C" void kernel_launch(void* const* d_in, const int* in_sizes, int n_in,
                              void* d_out, int out_size, void* d_ws, size_t ws_size,
                              hipStream_t stream) {
    const float* X = (const float*)d_in[0];   // [2048,4,4096] = [8192,4096]
    const float* W = (const float*)d_in[1];   // [64,4096]
    float* out   = (float*)d_out;
    float* Wt    = (float*)d_ws;                       // 262144 floats
    float* part  = Wt + (size_t)HDIM * NEXP;           // 8*8192*64 floats

    wtrans_kernel<<<HDIM / 64, 256, 0, stream>>>(W, Wt);
    logits_kernel<<<128 * HG, 256, 0, stream>>>(X, Wt, part);
    topk_kernel<<<NTOK / 4, 256, 0, stream>>>(part, out, out + (size_t)NTOK * NEXP);
}

// Round 2
// 228.210 us; speedup vs baseline: 1.3340x; 1.3340x over previous
//
#include <hip/hip_runtime.h>
#include <math.h>

// MoE router: X[8192,4096] fp32 @ Wt[4096,64] -> logits[8192,64] -> top2 -> softmax -> scatter.
// d_out = probs[8192*64] ++ routing_map[8192*64] (floats).
//
// ws layout: Wt (4096*64 floats = 1MB) | partial logits [8][8192][64] floats (16MB)
//
// R1 lesson: lane=token makes raw X reads stride-16KB per lane -> 4x overfetch
// (FETCH 517MB vs 134 ideal). Fix: block-cooperative coalesced staging of
// 64x64 X tiles into LDS; lanes read x from LDS (padded, 2-way = free).

#define HDIM 4096
#define NEXP 64
#define NTOK 8192
#define HG 8              // h-groups across blocks
#define HSLAB (HDIM / HG) // 512 h per block
#define NCHUNK (HSLAB / 64)  // 8 staged chunks of 64 h
#define TPB 64            // tokens per block (one per lane)

// ---------------- kernel 0: transpose W[64][4096] -> Wt[4096][64] ----------------
__global__ void wtrans_kernel(const float* __restrict__ W, float* __restrict__ Wt) {
    __shared__ float tile[64][65];
    int h0 = blockIdx.x * 64;
    int lx = threadIdx.x & 63;
    int ly = threadIdx.x >> 6;               // 0..3
    #pragma unroll
    for (int p = 0; p < 16; ++p) {
        int e = p * 4 + ly;
        tile[lx][e] = W[(size_t)e * HDIM + h0 + lx];   // coalesced over lx
    }
    __syncthreads();
    #pragma unroll
    for (int p = 0; p < 16; ++p) {
        int hh = p * 4 + ly;
        Wt[(size_t)(h0 + hh) * NEXP + lx] = tile[hh][lx];  // coalesced over lx
    }
}

// ---------------- kernel 1: partial logits ----------------
__global__ __launch_bounds__(256, 4) void logits_kernel(
        const float* __restrict__ X, const float* __restrict__ Wt,
        float* __restrict__ part) {
    const int tg   = blockIdx.x >> 3;        // token group 0..127
    const int hg   = blockIdx.x & 7;         // h group 0..7
    const int lane = threadIdx.x & 63;       // token within group
    const int wave = __builtin_amdgcn_readfirstlane((int)(threadIdx.x >> 6)); // 0..3

    // one LDS arena, two overlapping uses (disjoint in time):
    //   xs : 64 x 65 floats (16.6KB) x-tile during the FMA loop
    //   buf: 4 x 64 x 33 floats (33.8KB) slice-reduce at the end
    __shared__ float smem[4 * 64 * 33];      // 33792 B -> 4 blocks/CU
    float (*xs)[65]      = reinterpret_cast<float(*)[65]>(smem);
    float (*buf)[64][33] = reinterpret_cast<float(*)[64][33]>(smem);

    const int token0 = tg * TPB;
    const int hbase  = hg * HSLAB;

    float acc[NEXP];
    #pragma unroll
    for (int e = 0; e < NEXP; ++e) acc[e] = 0.f;

    const float* Xblk = X + (size_t)token0 * HDIM + hbase;
    const int r4 = threadIdx.x >> 4;         // 0..15
    const int f4 = threadIdx.x & 15;         // float4 slot in row

    for (int c = 0; c < NCHUNK; ++c) {
        __syncthreads();                     // xs safe to overwrite
        // stage 64 tokens x 64 h, coalesced: 16 lanes cover 256B contiguous
        #pragma unroll
        for (int q = 0; q < 4; ++q) {
            int r = q * 16 + r4;
            float4 v = *reinterpret_cast<const float4*>(
                Xblk + (size_t)r * HDIM + c * 64 + f4 * 4);
            xs[r][f4 * 4 + 0] = v.x;
            xs[r][f4 * 4 + 1] = v.y;
            xs[r][f4 * 4 + 2] = v.z;
            xs[r][f4 * 4 + 3] = v.w;
        }
        __syncthreads();
        // wave w handles h-local [w*16, w*16+16); W address wave-uniform -> s_load
        const float* wrow = Wt + (size_t)(hbase + c * 64 + wave * 16) * NEXP;
        #pragma unroll
        for (int j = 0; j < 16; ++j) {
            float xv = xs[lane][wave * 16 + j];   // bank (lane+const)%32: 2-way, free
            const float* w = wrow + (size_t)j * NEXP;
            #pragma unroll
            for (int e = 0; e < NEXP; ++e)
                acc[e] = fmaf(xv, w[e], acc[e]);  // SGPR-broadcast W
        }
    }

    // reduce the 4 wave-partials; expert-chunked (2 x 32). Fully unrolled so
    // acc[] indices are compile-time constants (keep acc in registers).
    #pragma unroll
    for (int cc = 0; cc < 2; ++cc) {
        __syncthreads();                     // protect smem reuse
        #pragma unroll
        for (int i = 0; i < 32; ++i) buf[wave][lane][i] = acc[cc * 32 + i];
        __syncthreads();
        int ec = threadIdx.x & 31;
        int t0 = threadIdx.x >> 5;           // 0..7
        #pragma unroll
        for (int p = 0; p < 8; ++p) {
            int t = p * 8 + t0;
            float s = buf[0][t][ec] + buf[1][t][ec] + buf[2][t][ec] + buf[3][t][ec];
            part[((size_t)hg * NTOK + (size_t)tg * TPB + t) * NEXP + cc * 32 + ec] = s;
        }
    }
}

// ---------------- kernel 2: reduce HG partials, top-2 softmax, scatter ----------------
__global__ __launch_bounds__(256) void topk_kernel(
        const float* __restrict__ part, float* __restrict__ probs,
        float* __restrict__ rmap) {
    const int wave = threadIdx.x >> 6;
    const int lane = threadIdx.x & 63;       // lane = expert
    const int token = blockIdx.x * 4 + wave;

    const float* p = part + (size_t)token * NEXP + lane;
    float v = 0.f;
    #pragma unroll
    for (int hg = 0; hg < HG; ++hg) v += p[(size_t)hg * NTOK * NEXP];

    // top-1 (lower index wins ties, like lax.top_k)
    float m1 = v; int i1 = lane;
    #pragma unroll
    for (int s = 32; s > 0; s >>= 1) {
        float om = __shfl_xor(m1, s, 64);
        int   oi = __shfl_xor(i1, s, 64);
        if (om > m1 || (om == m1 && oi < i1)) { m1 = om; i1 = oi; }
    }
    // top-2: exclude i1
    float vx = (lane == i1) ? -INFINITY : v;
    float m2 = vx; int i2 = lane;
    #pragma unroll
    for (int s = 32; s > 0; s >>= 1) {
        float om = __shfl_xor(m2, s, 64);
        int   oi = __shfl_xor(i2, s, 64);
        if (om > m2 || (om == m2 && oi < i2)) { m2 = om; i2 = oi; }
    }

    // softmax over (m1, m2); m2 - m1 <= 0 so expf is safe
    float e2 = expf(m2 - m1);
    float p1 = 1.f / (1.f + e2);
    float p2 = 1.f - p1;

    float prob = (lane == i1) ? p1 : ((lane == i2) ? p2 : 0.f);
    float flag = (lane == i1 || lane == i2) ? 1.f : 0.f;
    probs[(size_t)token * NEXP + lane] = prob;   // coalesced 64 dwords
    rmap [(size_t)token * NEXP + lane] = flag;
}

extern "C" void kernel_launch(void* const* d_in, const int* in_sizes, int n_in,
                              void* d_out, int out_size, void* d_ws, size_t ws_size,
                              hipStream_t stream) {
    const float* X = (const float*)d_in[0];   // [2048,4,4096] = [8192,4096]
    const float* W = (const float*)d_in[1];   // [64,4096]
    float* out   = (float*)d_out;
    float* Wt    = (float*)d_ws;                       // 262144 floats
    float* part  = Wt + (size_t)HDIM * NEXP;           // 8*8192*64 floats

    wtrans_kernel<<<HDIM / 64, 256, 0, stream>>>(W, Wt);
    logits_kernel<<<128 * HG, 256, 0, stream>>>(X, Wt, part);
    topk_kernel<<<NTOK / 4, 256, 0, stream>>>(part, out, out + (size_t)NTOK * NEXP);
}